// Round 3
// baseline (184.840 us; speedup 1.0000x reference)
//
#include <hip/hip_runtime.h>
#include <math.h>

#define THRESH 0.65f

// ws layout (float offsets):
// cellscore: [0, 8192)      32 maps x 256 cells
// cellidx:   [8192, 16384)  (int)
// bgval:     [16384, 16896) 32 maps x 16 stripe partials
// bgidx:     [16896, 17408) (int)
// counters:  [17408, 17440) 32 ints, memset to 0 each launch

// Fused kernel: grid (16 cellrows, 32 maps) x 256 threads, 2 blocks/CU.
// Phase A: ref-norm + 6 sim rows (halo-clamped) + bilinear cell argmax +
//          stripe bg-min. Phase B (last block per map): rank-sort + bg merge.
__global__ __launch_bounds__(256) void k_fused(const float* __restrict__ feat,
                                               const float* __restrict__ ref,
                                               float* __restrict__ cellscore,
                                               int* __restrict__ cellidx,
                                               float* __restrict__ bgval,
                                               int* __restrict__ bgidx,
                                               int* __restrict__ counters,
                                               float* __restrict__ out) {
    __shared__ float rn[256];       // normalized ref row
    __shared__ float S[6 * 65];     // 6 sim rows, stride 65 (bank-conflict pad)
    __shared__ float red[256];      // reductions; reused as sc[] in phase B
    __shared__ float wmin[4];
    __shared__ int wmini[4];
    __shared__ int lastFlag;

    int t = threadIdx.x;
    int cy = blockIdx.x;   // 0..15
    int m  = blockIdx.y;   // 0..31

    // --- ref L2-normalize (identical arithmetic to round 2) ---
    float v = ref[m * 256 + t];
    red[t] = v * v;
    __syncthreads();
    for (int s = 128; s > 0; s >>= 1) {
        if (t < s) red[t] += red[t + s];
        __syncthreads();
    }
    float den = sqrtf(red[0]) + 1e-12f;
    __syncthreads();
    rn[t] = v / den;
    __syncthreads();

    // --- sim for 6 rows (with clamped halo), feat dotted with rn ---
    int ybase = 4 * cy - 1;
    for (int slot = t; slot < 384; slot += 256) {
        int j = slot >> 6, col = slot & 63;
        int gy = min(max(ybase + j, 0), 63);
        const float* fp = feat + gy * 64 + col;
        float dot = 0.f, nsq = 0.f;
        for (int g = 0; g < 16; ++g) {
            float p = 0.f, nq = 0.f;
#pragma unroll
            for (int cc = 0; cc < 16; ++cc) {
                int c = g * 16 + cc;
                float fv = fp[c * 4096];
                p += fv * rn[c];
                nq += fv * fv;
            }
            dot += p; nsq += nq;
        }
        S[j * 65 + col] = dot / (sqrtf(nsq) + 1e-12f);
    }
    __syncthreads();

    // --- bilinear upsample scan: thread = (cell cx = t>>4, subrow r = t&15) ---
    int cx = t >> 4, r = t & 15;
    int xbase = 4 * cx - 1;
    const int lstart[5] = {0, 8, 24, 40, 56};
    const int lend[5]   = {8, 24, 40, 56, 64};

    float bmax = -1e30f; int bmaxi = 0;
    float bmin = 1e30f;  int bmini = 0;
    for (int rr = 0; rr < 4; ++rr) {
        int lyy = r * 4 + rr;       // local row in cell 0..63
        int oy = cy * 64 + lyy;     // global output row
        float fy = (oy + 0.5f) * 0.0625f - 0.5f;  // exact dyadic
        float y0f = floorf(fy);
        int y0 = (int)y0f;
        float wy = fy - y0f;
        bool ylo = fy < 0.0f, yhi = fy > 63.0f;
        int py0 = min(max(y0, 0), 63) - ybase;      // 0..5
        int py1 = min(max(y0 + 1, 0), 63) - ybase;  // 0..5
        const float* P0 = S + py0 * 65;
        const float* P1 = S + py1 * 65;
        float w1y = 1.0f - wy;
#pragma unroll
        for (int s5 = 0; s5 < 5; ++s5) {
            int x0 = xbase + s5;
            int c0 = min(max(x0, 0), 63);
            int c1 = min(max(x0 + 1, 0), 63);
            float a = P0[c0], b = P0[c1];
            float c = P1[c0], d = P1[c1];
            // y-combine first (mirrors reference), exact edge passthrough
            float q0 = ylo ? a : (yhi ? c : w1y * a + wy * c);
            float q1 = ylo ? b : (yhi ? d : w1y * b + wy * d);
            float x0f = (float)x0;
            for (int l = lstart[s5]; l < lend[s5]; ++l) {
                int ox = cx * 64 + l;
                float fx = (ox + 0.5f) * 0.0625f - 0.5f;
                float wx = fx - x0f;
                float vv;
                if (fx < 0.0f)        vv = q1;  // single tap at col 0
                else if (fx > 63.0f)  vv = q0;  // single tap at col 63
                else                  vv = (1.0f - wx) * q0 + wx * q1;
                int li = lyy * 64 + l;
                if (vv > bmax) { bmax = vv; bmaxi = li; }
                if (vv < bmin) { bmin = vv; bmini = oy * 1024 + ox; }
            }
        }
    }
    // per-cell argmax over 16 subrow threads (width-16), lower index wins ties
    for (int off = 8; off > 0; off >>= 1) {
        float ov = __shfl_down(bmax, off, 16);
        int   oi = __shfl_down(bmaxi, off, 16);
        if (ov > bmax || (ov == bmax && oi < bmaxi)) { bmax = ov; bmaxi = oi; }
    }
    if (r == 0) {
        int cell = cy * 16 + cx;
        cellscore[m * 256 + cell] = bmax;
        cellidx[m * 256 + cell] = bmaxi;
    }
    // stripe-wide bg min: wave reduce then cross-wave via LDS
    for (int off = 32; off > 0; off >>= 1) {
        float mv = __shfl_down(bmin, off);
        int   mj = __shfl_down(bmini, off);
        if (mv < bmin || (mv == bmin && mj < bmini)) { bmin = mv; bmini = mj; }
    }
    int wid = t >> 6;
    if ((t & 63) == 0) { wmin[wid] = bmin; wmini[wid] = bmini; }
    __syncthreads();
    if (t == 0) {
        float bv = wmin[0]; int bi = wmini[0];
        for (int w = 1; w < 4; ++w) {
            if (wmin[w] < bv || (wmin[w] == bv && wmini[w] < bi)) {
                bv = wmin[w]; bi = wmini[w];
            }
        }
        bgval[m * 16 + cy] = bv;
        bgidx[m * 16 + cy] = bi;
    }
    // --- release: stores drained by barrier, then fence + count ---
    __syncthreads();
    if (t == 0) {
        __threadfence();
        int old = atomicAdd(&counters[m], 1);
        lastFlag = (old == 15) ? 1 : 0;
    }
    __syncthreads();
    if (!lastFlag) return;

    // --- Phase B (last block of map m): acquire + sort + bg merge ---
    __threadfence();
    float score = cellscore[m * 256 + t];
    int li = cellidx[m * 256 + t];
    int pcy = t >> 4, pcx = t & 15;
    int ly = li >> 6, lx = li & 63;
    bool valid = score > THRESH;
    float px = valid ? (float)(pcx * 64 + lx) : -1.0f;
    float py = valid ? (float)(pcy * 64 + ly) : -1.0f;
    float ps = valid ? score : -1.0f;
    __syncthreads();           // red[] reuse
    red[t] = ps;
    __syncthreads();
    // stable descending rank: key (-score, cell_id)
    int rank = 0;
    for (int j = 0; j < 256; ++j) {
        float sj = red[j];
        rank += (sj > ps || (sj == ps && j < t)) ? 1 : 0;
    }
    float* o = out + m * 768 + rank * 3;
    o[0] = px; o[1] = py; o[2] = ps;
    if (t == 0) {
        float bv = bgval[m * 16]; int bi = bgidx[m * 16];
        for (int w = 1; w < 16; ++w) {
            float v2 = bgval[m * 16 + w]; int i2 = bgidx[m * 16 + w];
            if (v2 < bv || (v2 == bv && i2 < bi)) { bv = v2; bi = i2; }
        }
        out[24576 + m * 2 + 0] = (float)(bi % 1024);  // x = col
        out[24576 + m * 2 + 1] = (float)(bi / 1024);  // y = row
    }
}

extern "C" void kernel_launch(void* const* d_in, const int* in_sizes, int n_in,
                              void* d_out, int out_size, void* d_ws, size_t ws_size,
                              hipStream_t stream) {
    const float* feat = (const float*)d_in[0];  // (1,256,64,64)
    const float* ref  = (const float*)d_in[1];  // (32,1,256)
    if (in_sizes[0] == 32 * 256) {  // defensive: swap if order reversed
        feat = (const float*)d_in[1];
        ref  = (const float*)d_in[0];
    }
    float* out = (float*)d_out;
    float* ws = (float*)d_ws;
    float* cellscore = ws;
    int*   cellidx   = (int*)(ws + 8192);
    float* bgval     = ws + 16384;
    int*   bgidx     = (int*)(ws + 16896);
    int*   counters  = (int*)(ws + 17408);

    hipMemsetAsync(counters, 0, 32 * sizeof(int), stream);
    k_fused<<<dim3(16, 32), 256, 0, stream>>>(feat, ref, cellscore, cellidx,
                                              bgval, bgidx, counters, out);
}

// Round 4
// 104.606 us; speedup vs baseline: 1.7670x; 1.7670x over previous
//
#include <hip/hip_runtime.h>
#include <math.h>

#define THRESH 0.65f

// ws layout (float offsets):
// cellscore: [0, 8192)      32 maps x 256 cells
// cellidx:   [8192, 16384)  (int)
// bgval:     [16384, 17408) 32 maps x 32 stripe partials
// bgidx:     [17408, 18432) (int)

// K1: grid (32, 32) x 256 threads = 1024 blocks (4 blocks/CU).
// blockIdx.x = cy*2 + h : cell row cy (0..15), half h (0..1) -> 8 cells.
// blockIdx.y = map m (0..31).
// Computes the needed 6 sim rows x 34 cols (halo, clamp baked in) from feat,
// then bilinear-upsample scan: per-cell argmax + half-stripe bg argmin.
// All float arithmetic is byte-identical to the round-2 kernel (absmax 0.0).
__global__ __launch_bounds__(256) void k_main(const float* __restrict__ feat,
                                              const float* __restrict__ ref,
                                              float* __restrict__ cellscore,
                                              int* __restrict__ cellidx,
                                              float* __restrict__ bgval,
                                              int* __restrict__ bgidx) {
    __shared__ float rn[256];      // normalized ref row
    __shared__ float S[6 * 35];    // 6 sim rows x 34 cols, stride 35 (pad)
    __shared__ float red[256];
    __shared__ float wmin[4];
    __shared__ int wmini[4];

    int t = threadIdx.x;
    int cy = blockIdx.x >> 1;
    int h  = blockIdx.x & 1;
    int m  = blockIdx.y;

    // --- ref L2-normalize (identical arithmetic to round 2) ---
    float v = ref[m * 256 + t];
    red[t] = v * v;
    __syncthreads();
    for (int s = 128; s > 0; s >>= 1) {
        if (t < s) red[t] += red[t + s];
        __syncthreads();
    }
    float den = sqrtf(red[0]) + 1e-12f;
    __syncthreads();
    rn[t] = v / den;
    __syncthreads();

    // --- sim for 6 rows x 34 cols (clamped halo baked into storage) ---
    // local col j <-> global col (32*h - 1 + j), clamped to [0,63]
    int ybase = 4 * cy - 1;
    int xgbase = 32 * h - 1;
    if (t < 204) {
        int j = t / 34, col = t - 34 * j;
        int gy = min(max(ybase + j, 0), 63);
        int gx = min(max(xgbase + col, 0), 63);
        const float* fp = feat + gy * 64 + gx;
        float dot = 0.f, nsq = 0.f;
        for (int g = 0; g < 16; ++g) {
            float p = 0.f, nq = 0.f;
#pragma unroll
            for (int cc = 0; cc < 16; ++cc) {
                int c = g * 16 + cc;
                float fv = fp[c * 4096];
                p += fv * rn[c];
                nq += fv * fv;
            }
            dot += p; nsq += nq;
        }
        S[j * 35 + col] = dot / (sqrtf(nsq) + 1e-12f);
    }
    __syncthreads();

    // --- bilinear scan: thread = (local cell cxl = t>>5, subrow r = t&31) ---
    int cxl = t >> 5, r = t & 31;
    int cx = 8 * h + cxl;            // global cell col
    int xbase = 4 * cx - 1;          // global first x-tap
    const int lstart[5] = {0, 8, 24, 40, 56};
    const int lend[5]   = {8, 24, 40, 56, 64};

    float bmax = -1e30f; int bmaxi = 0;
    float bmin = 1e30f;  int bmini = 0;
    for (int rr = 0; rr < 2; ++rr) {
        int lyy = r * 2 + rr;        // local row in cell 0..63
        int oy = cy * 64 + lyy;      // global output row
        float fy = (oy + 0.5f) * 0.0625f - 0.5f;  // exact dyadic
        float y0f = floorf(fy);
        int y0 = (int)y0f;
        float wy = fy - y0f;
        bool ylo = fy < 0.0f, yhi = fy > 63.0f;
        int py0 = min(max(y0, 0), 63) - ybase;      // 0..5
        int py1 = min(max(y0 + 1, 0), 63) - ybase;  // 0..5
        const float* P0 = S + py0 * 35;
        const float* P1 = S + py1 * 35;
        float w1y = 1.0f - wy;
#pragma unroll
        for (int s5 = 0; s5 < 5; ++s5) {
            int x0 = xbase + s5;
            int i0 = 4 * cxl + s5;   // local index of x0 (clamp baked in)
            float a = P0[i0], b = P0[i0 + 1];
            float c = P1[i0], d = P1[i0 + 1];
            // y-combine first (mirrors reference), exact edge passthrough
            float q0 = ylo ? a : (yhi ? c : w1y * a + wy * c);
            float q1 = ylo ? b : (yhi ? d : w1y * b + wy * d);
            float x0f = (float)x0;
            for (int l = lstart[s5]; l < lend[s5]; ++l) {
                int ox = cx * 64 + l;
                float fx = (ox + 0.5f) * 0.0625f - 0.5f;
                float wx = fx - x0f;
                float vv;
                if (fx < 0.0f)        vv = q1;  // single tap at col 0
                else if (fx > 63.0f)  vv = q0;  // single tap at col 63
                else                  vv = (1.0f - wx) * q0 + wx * q1;
                int li = lyy * 64 + l;
                if (vv > bmax) { bmax = vv; bmaxi = li; }
                if (vv < bmin) { bmin = vv; bmini = oy * 1024 + ox; }
            }
        }
    }
    // per-cell argmax over 32 subrow threads (width-32 segments align with
    // cells); lower li wins ties -> first-occurrence semantics
    for (int off = 16; off > 0; off >>= 1) {
        float ov = __shfl_down(bmax, off, 32);
        int   oi = __shfl_down(bmaxi, off, 32);
        if (ov > bmax || (ov == bmax && oi < bmaxi)) { bmax = ov; bmaxi = oi; }
    }
    if (r == 0) {
        int cell = cy * 16 + cx;
        cellscore[m * 256 + cell] = bmax;
        cellidx[m * 256 + cell] = bmaxi;
    }
    // half-stripe bg min: wave reduce then cross-wave via LDS
    for (int off = 32; off > 0; off >>= 1) {
        float mv = __shfl_down(bmin, off);
        int   mj = __shfl_down(bmini, off);
        if (mv < bmin || (mv == bmin && mj < bmini)) { bmin = mv; bmini = mj; }
    }
    int wid = t >> 6;
    if ((t & 63) == 0) { wmin[wid] = bmin; wmini[wid] = bmini; }
    __syncthreads();
    if (t == 0) {
        float bv = wmin[0]; int bi = wmini[0];
        for (int w = 1; w < 4; ++w) {
            if (wmin[w] < bv || (wmin[w] == bv && wmini[w] < bi)) {
                bv = wmin[w]; bi = wmini[w];
            }
        }
        bgval[m * 32 + blockIdx.x] = bv;
        bgidx[m * 32 + blockIdx.x] = bi;
    }
}

// K2: 32 blocks (one per map) x 256 threads (one per cell):
// threshold + stable descending rank-sort + bg merge over 32 partials.
__global__ __launch_bounds__(256) void k_out(const float* __restrict__ cellscore,
                                             const int* __restrict__ cellidx,
                                             const float* __restrict__ bgval,
                                             const int* __restrict__ bgidx,
                                             float* __restrict__ out) {
    __shared__ float sc[256];
    int m = blockIdx.x, t = threadIdx.x;
    float score = cellscore[m * 256 + t];
    int li = cellidx[m * 256 + t];
    int cy = t >> 4, cx = t & 15;
    int ly = li >> 6, lx = li & 63;
    bool valid = score > THRESH;
    float px = valid ? (float)(cx * 64 + lx) : -1.0f;
    float py = valid ? (float)(cy * 64 + ly) : -1.0f;
    float ps = valid ? score : -1.0f;
    sc[t] = ps;
    __syncthreads();
    // stable descending rank: key (-score, cell_id)
    int rank = 0;
    for (int j = 0; j < 256; ++j) {
        float sj = sc[j];
        rank += (sj > ps || (sj == ps && j < t)) ? 1 : 0;
    }
    float* o = out + m * 768 + rank * 3;
    o[0] = px; o[1] = py; o[2] = ps;
    // bg: lexicographic min (val, flat idx) over 32 partials
    if (t == 0) {
        float bv = bgval[m * 32]; int bi = bgidx[m * 32];
        for (int w = 1; w < 32; ++w) {
            float v = bgval[m * 32 + w]; int i2 = bgidx[m * 32 + w];
            if (v < bv || (v == bv && i2 < bi)) { bv = v; bi = i2; }
        }
        out[24576 + m * 2 + 0] = (float)(bi % 1024);  // x = col
        out[24576 + m * 2 + 1] = (float)(bi / 1024);  // y = row
    }
}

extern "C" void kernel_launch(void* const* d_in, const int* in_sizes, int n_in,
                              void* d_out, int out_size, void* d_ws, size_t ws_size,
                              hipStream_t stream) {
    const float* feat = (const float*)d_in[0];  // (1,256,64,64)
    const float* ref  = (const float*)d_in[1];  // (32,1,256)
    if (in_sizes[0] == 32 * 256) {  // defensive: swap if order reversed
        feat = (const float*)d_in[1];
        ref  = (const float*)d_in[0];
    }
    float* out = (float*)d_out;
    float* ws = (float*)d_ws;
    float* cellscore = ws;
    int*   cellidx   = (int*)(ws + 8192);
    float* bgval     = ws + 16384;
    int*   bgidx     = (int*)(ws + 17408);

    k_main<<<dim3(32, 32), 256, 0, stream>>>(feat, ref, cellscore, cellidx, bgval, bgidx);
    k_out<<<32, 256, 0, stream>>>(cellscore, cellidx, bgval, bgidx, out);
}

// Round 5
// 79.489 us; speedup vs baseline: 2.3254x; 1.3160x over previous
//
#include <hip/hip_runtime.h>
#include <math.h>

#define THRESH 0.65f

// ws float offsets:
// sim       [0, 131072)        32 maps x 4096
// cellscore [131072, 139264)   32 x 256
// cellidx   [139264, 147456)   (int)
// bgval     [147456, 149504)   32 x 64 block partials
// bgidx     [149504, 151552)   (int)

// K1: grid (32 px-groups of 128, 16 map-pairs) x 256 threads.
// Thread t: px = bx*128 + (t>>1), map = m0 + (t&1). Each feat value is loaded
// once per lane-pair (serves 2 maps) -> 64 MB total L2 traffic.
__global__ __launch_bounds__(256) void k_sim(const float* __restrict__ feat,
                                             const float* __restrict__ ref,
                                             float* __restrict__ sim) {
    __shared__ float rnS[2][256];
    __shared__ float red[256];
    int t = threadIdx.x;
    int m0 = blockIdx.y * 2;

    float v0 = ref[m0 * 256 + t];
    float v1 = ref[(m0 + 1) * 256 + t];
    red[t] = v0 * v0;
    __syncthreads();
    for (int s = 128; s > 0; s >>= 1) { if (t < s) red[t] += red[t + s]; __syncthreads(); }
    float den0 = sqrtf(red[0]) + 1e-12f;
    __syncthreads();
    red[t] = v1 * v1;
    __syncthreads();
    for (int s = 128; s > 0; s >>= 1) { if (t < s) red[t] += red[t + s]; __syncthreads(); }
    float den1 = sqrtf(red[0]) + 1e-12f;
    rnS[0][t] = v0 / den0;
    rnS[1][t] = v1 / den1;
    __syncthreads();

    int px = blockIdx.x * 128 + (t >> 1);
    int mi = t & 1;
    const float* fp = feat + px;
    const float* rn = rnS[mi];
    float dot = 0.f, nsq = 0.f;
    for (int g = 0; g < 16; ++g) {
        float p = 0.f, nq = 0.f;
#pragma unroll
        for (int cc = 0; cc < 16; ++cc) {
            int c = g * 16 + cc;
            float fv = fp[c * 4096];
            p += fv * rn[c];
            nq += fv * fv;
        }
        dot += p; nsq += nq;
    }
    sim[(m0 + mi) * 4096 + px] = dot / (sqrtf(nsq) + 1e-12f);
}

// K2: grid (64, 32) x 256 threads; bx -> (cy = bx>>2, quarter qx = bx&3).
// Wave = one cell (cx = qx*4 + wave_id), lane = output row r in cell.
// Segment-endpoint evaluation: within a fixed-(q0,q1) x-segment, the bilinear
// value is linear in wx (exact dyadic constants), so max/min are at endpoints.
// Endpoints are evaluated with the formula (1-wx)*q0 + wx*q1 with exact
// constants == the reference's per-sample arithmetic at those samples.
__global__ __launch_bounds__(256) void k_scan(const float* __restrict__ sim,
                                              float* __restrict__ cellscore,
                                              int* __restrict__ cellidx,
                                              float* __restrict__ bgval,
                                              int* __restrict__ bgidx) {
    __shared__ float S[6 * 19];   // 6 sim rows x 18 cols (+1 pad)
    __shared__ float wmin[4];
    __shared__ int wmini[4];

    int t = threadIdx.x;
    int bx = blockIdx.x;
    int cy = bx >> 2, qx = bx & 3;
    int m = blockIdx.y;
    int ybase = 4 * cy - 1;
    int xgbase = 16 * qx - 1;
    const float* sm = sim + m * 4096;

    if (t < 108) {
        int j = t / 18, col = t - 18 * j;
        int gy = min(max(ybase + j, 0), 63);
        int gx = min(max(xgbase + col, 0), 63);
        S[j * 19 + col] = sm[gy * 64 + gx];
    }
    __syncthreads();

    int cxl = t >> 6, r = t & 63;
    int cx = qx * 4 + cxl;
    int oy = cy * 64 + r;
    float fy = (oy + 0.5f) * 0.0625f - 0.5f;  // exact dyadic
    float y0f = floorf(fy);
    float wy = fy - y0f;
    bool ylo = fy < 0.0f, yhi = fy > 63.0f;
    int y0 = (int)y0f;
    int py0 = min(max(y0, 0), 63) - ybase;
    int py1 = min(max(y0 + 1, 0), 63) - ybase;
    const float* P0 = S + py0 * 19;
    const float* P1 = S + py1 * 19;
    float w1y = 1.0f - wy;

    // segment tables: first/last sample l and exact wx at those samples
    const int   L0[5]  = {0, 8, 24, 40, 56};
    const int   L1[5]  = {7, 23, 39, 55, 63};
    const float WXA[5] = {0.53125f, 0.03125f, 0.03125f, 0.03125f, 0.03125f};
    const float WXB[5] = {0.96875f, 0.96875f, 0.96875f, 0.96875f, 0.46875f};
    const float WCA[5] = {0.46875f, 0.96875f, 0.96875f, 0.96875f, 0.96875f};  // 1-WXA
    const float WCB[5] = {0.03125f, 0.03125f, 0.03125f, 0.03125f, 0.53125f};  // 1-WXB

    bool xlo = (cx == 0), xhi = (cx == 15);
    float bmax = -1e30f; int bmaxi = 0;
    float bmin = 1e30f;  int bmini = 0;
    int libase = r * 64;
    int rowbase = oy * 1024 + cx * 64;

#pragma unroll
    for (int s5 = 0; s5 < 5; ++s5) {
        int i0 = 4 * cxl + s5;
        float a = P0[i0], b = P0[i0 + 1];
        float c = P1[i0], d = P1[i0 + 1];
        // y-combine first (mirrors reference), exact edge passthrough
        float q0 = ylo ? a : (yhi ? c : w1y * a + wy * c);
        float q1 = ylo ? b : (yhi ? d : w1y * b + wy * d);
        float va, vb;
        if (xlo && s5 == 0)      { va = q1; vb = q1; }  // fx<0: single tap
        else if (xhi && s5 == 4) { va = q0; vb = q0; }  // fx>63: single tap
        else {
            va = WCA[s5] * q0 + WXA[s5] * q1;
            vb = WCB[s5] * q0 + WXB[s5] * q1;
        }
        // segment extrema at endpoints (linear in wx); ties -> first sample
        float smax, smin; int smaxl, sminl;
        if (va >= vb) { smax = va; smaxl = L0[s5]; } else { smax = vb; smaxl = L1[s5]; }
        if (va <= vb) { smin = va; sminl = L0[s5]; } else { smin = vb; sminl = L1[s5]; }
        if (smax > bmax) { bmax = smax; bmaxi = libase + smaxl; }
        if (smin < bmin) { bmin = smin; bmini = rowbase + sminl; }
    }

    // per-cell (wave) reduce; lower index wins ties
    for (int off = 32; off > 0; off >>= 1) {
        float ov = __shfl_down(bmax, off);
        int   oi = __shfl_down(bmaxi, off);
        if (ov > bmax || (ov == bmax && oi < bmaxi)) { bmax = ov; bmaxi = oi; }
        float mv = __shfl_down(bmin, off);
        int   mj = __shfl_down(bmini, off);
        if (mv < bmin || (mv == bmin && mj < bmini)) { bmin = mv; bmini = mj; }
    }
    if (r == 0) {
        int cell = cy * 16 + cx;
        cellscore[m * 256 + cell] = bmax;
        cellidx[m * 256 + cell] = bmaxi;
        wmin[cxl] = bmin;
        wmini[cxl] = bmini;
    }
    __syncthreads();
    if (t == 0) {
        float bv = wmin[0]; int bi = wmini[0];
        for (int w = 1; w < 4; ++w) {
            if (wmin[w] < bv || (wmin[w] == bv && wmini[w] < bi)) {
                bv = wmin[w]; bi = wmini[w];
            }
        }
        bgval[m * 64 + bx] = bv;
        bgidx[m * 64 + bx] = bi;
    }
}

// K3: 32 blocks x 256 threads: threshold + stable descending rank + bg merge.
__global__ __launch_bounds__(256) void k_out(const float* __restrict__ cellscore,
                                             const int* __restrict__ cellidx,
                                             const float* __restrict__ bgval,
                                             const int* __restrict__ bgidx,
                                             float* __restrict__ out) {
    __shared__ float sc[256];
    __shared__ float mv[64];
    __shared__ int mi_[64];
    int m = blockIdx.x, t = threadIdx.x;
    float score = cellscore[m * 256 + t];
    int li = cellidx[m * 256 + t];
    int cy = t >> 4, cx = t & 15;
    int ly = li >> 6, lx = li & 63;
    bool valid = score > THRESH;
    float px = valid ? (float)(cx * 64 + lx) : -1.0f;
    float py = valid ? (float)(cy * 64 + ly) : -1.0f;
    float ps = valid ? score : -1.0f;
    sc[t] = ps;
    if (t < 64) { mv[t] = bgval[m * 64 + t]; mi_[t] = bgidx[m * 64 + t]; }
    __syncthreads();
    // stable descending rank: key (-score, cell_id)
    int rank = 0;
    for (int j = 0; j < 256; ++j) {
        float sj = sc[j];
        rank += (sj > ps || (sj == ps && j < t)) ? 1 : 0;
    }
    float* o = out + m * 768 + rank * 3;
    o[0] = px; o[1] = py; o[2] = ps;
    // bg: lexicographic min (val, flat idx) over 64 partials
    for (int s = 32; s > 0; s >>= 1) {
        __syncthreads();
        if (t < s) {
            float v2 = mv[t + s]; int i2 = mi_[t + s];
            if (v2 < mv[t] || (v2 == mv[t] && i2 < mi_[t])) { mv[t] = v2; mi_[t] = i2; }
        }
    }
    __syncthreads();
    if (t == 0) {
        int bi = mi_[0];
        out[24576 + m * 2 + 0] = (float)(bi % 1024);  // x = col
        out[24576 + m * 2 + 1] = (float)(bi / 1024);  // y = row
    }
}

extern "C" void kernel_launch(void* const* d_in, const int* in_sizes, int n_in,
                              void* d_out, int out_size, void* d_ws, size_t ws_size,
                              hipStream_t stream) {
    const float* feat = (const float*)d_in[0];  // (1,256,64,64)
    const float* ref  = (const float*)d_in[1];  // (32,1,256)
    if (in_sizes[0] == 32 * 256) {  // defensive: swap if order reversed
        feat = (const float*)d_in[1];
        ref  = (const float*)d_in[0];
    }
    float* out = (float*)d_out;
    float* ws = (float*)d_ws;
    float* sim       = ws;
    float* cellscore = ws + 131072;
    int*   cellidx   = (int*)(ws + 139264);
    float* bgval     = ws + 147456;
    int*   bgidx     = (int*)(ws + 149504);

    k_sim<<<dim3(32, 16), 256, 0, stream>>>(feat, ref, sim);
    k_scan<<<dim3(64, 32), 256, 0, stream>>>(sim, cellscore, cellidx, bgval, bgidx);
    k_out<<<32, 256, 0, stream>>>(cellscore, cellidx, bgval, bgidx, out);
}

// Round 6
// 74.239 us; speedup vs baseline: 2.4898x; 1.0707x over previous
//
#include <hip/hip_runtime.h>
#include <math.h>

#define THRESH 0.65f

// ws float offsets:
// sim [0, 131072)  32 maps x 4096   (only ws use)

// K1: grid (32 px-chunks of 128, 16 map-pairs) x 256 threads.
// Thread t = (channel-half h = t>>7, pxl = t&127). Each feat value is loaded
// once and feeds dot(map0), dot(map1), and nsq -> no redundant norm work.
__global__ __launch_bounds__(256) void k_sim(const float* __restrict__ feat,
                                             const float* __restrict__ ref,
                                             float* __restrict__ sim) {
    __shared__ float rn0[256], rn1[256], red[256];
    __shared__ float pd0[256], pd1[256], pn[256];
    int t = threadIdx.x;
    int m0 = blockIdx.y * 2;

    float v0 = ref[m0 * 256 + t];
    float v1 = ref[(m0 + 1) * 256 + t];
    red[t] = v0 * v0;
    __syncthreads();
    for (int s = 128; s > 0; s >>= 1) { if (t < s) red[t] += red[t + s]; __syncthreads(); }
    float den0 = sqrtf(red[0]) + 1e-12f;
    __syncthreads();
    red[t] = v1 * v1;
    __syncthreads();
    for (int s = 128; s > 0; s >>= 1) { if (t < s) red[t] += red[t + s]; __syncthreads(); }
    float den1 = sqrtf(red[0]) + 1e-12f;
    rn0[t] = v0 / den0;
    rn1[t] = v1 / den1;
    __syncthreads();

    int half = t >> 7, pxl = t & 127;
    int px = blockIdx.x * 128 + pxl;
    const float* fp = feat + px + half * 128 * 4096;
    const float* r0 = rn0 + half * 128;
    const float* r1 = rn1 + half * 128;
    float d0 = 0.f, d1 = 0.f, nq = 0.f;
    for (int g = 0; g < 8; ++g) {
#pragma unroll
        for (int cc = 0; cc < 16; ++cc) {
            int c = g * 16 + cc;
            float fv = fp[c * 4096];
            d0 += fv * r0[c];
            d1 += fv * r1[c];
            nq += fv * fv;
        }
    }
    pd0[t] = d0; pd1[t] = d1; pn[t] = nq;
    __syncthreads();
    float D0 = pd0[pxl] + pd0[pxl + 128];
    float D1 = pd1[pxl] + pd1[pxl + 128];
    float NQ = pn[pxl] + pn[pxl + 128];
    float den = sqrtf(NQ) + 1e-12f;
    sim[(m0 + half) * 4096 + px] = (half ? D1 : D0) / den;
}

// K2: 32 blocks (one per map) x 256 threads (thread = cell).
// 2D segment-corner evaluation: v is bilinear within each (y-seg x x-seg)
// rectangle (exact dyadic weights), so extrema are at the 4 corners. Corners
// are evaluated with the reference's own per-sample formula (y-combine then
// x-combine, single-tap clamp passthrough). Candidates visited in global
// row-major order with strict compares -> first-occurrence tie semantics.
// Sort + bg argmin are block-local (whole map in one block).
__global__ __launch_bounds__(256) void k_scan_out(const float* __restrict__ sim,
                                                  float* __restrict__ out) {
    __shared__ float S[64 * 65];   // sim map, stride 65 (bank pad)
    __shared__ float sc[256];
    __shared__ float wmin[4];
    __shared__ int wmini[4];

    int m = blockIdx.x, t = threadIdx.x;
    const float* sm = sim + m * 4096;
    for (int k = 0; k < 16; ++k) {
        int f = t + 256 * k;
        S[(f >> 6) * 65 + (f & 63)] = sm[f];
    }
    __syncthreads();

    int cy = t >> 4, cx = t & 15;
    int gxs[6];
#pragma unroll
    for (int j = 0; j < 6; ++j) {
        int g = 4 * cx - 1 + j;
        gxs[j] = min(max(g, 0), 63);
    }
    const int   L0[5]  = {0, 8, 24, 40, 56};
    const int   L1[5]  = {7, 23, 39, 55, 63};
    const float WXA[5] = {0.53125f, 0.03125f, 0.03125f, 0.03125f, 0.03125f};
    const float WXB[5] = {0.96875f, 0.96875f, 0.96875f, 0.96875f, 0.46875f};
    const float WCA[5] = {0.46875f, 0.96875f, 0.96875f, 0.96875f, 0.96875f};
    const float WCB[5] = {0.03125f, 0.03125f, 0.03125f, 0.03125f, 0.53125f};

    float bmax = -1e30f, bmin = 1e30f;
    int bmaxi = 0, bmini = 0;
#pragma unroll
    for (int sy = 0; sy < 5; ++sy) {
#pragma unroll
        for (int e = 0; e < 2; ++e) {
            int r = e ? L1[sy] : L0[sy];      // corner row (cell-local)
            int oy = cy * 64 + r;
            float fy = (oy + 0.5f) * 0.0625f - 0.5f;  // exact dyadic
            float y0f = floorf(fy);
            float wy = fy - y0f, w1y = 1.0f - wy;
            bool ylo = fy < 0.0f, yhi = fy > 63.0f;
            int y0 = (int)y0f;
            const float* P0 = S + min(max(y0, 0), 63) * 65;
            const float* P1 = S + min(max(y0 + 1, 0), 63) * 65;
            float q[6];
#pragma unroll
            for (int j = 0; j < 6; ++j) {
                float a = P0[gxs[j]], c = P1[gxs[j]];
                q[j] = ylo ? a : (yhi ? c : w1y * a + wy * c);
            }
#pragma unroll
            for (int s5 = 0; s5 < 5; ++s5) {
                float q0 = q[s5], q1 = q[s5 + 1];
                float va, vb;
                if (cx == 0 && s5 == 0)       { va = q1; vb = q1; }  // fx<0 single tap
                else if (cx == 15 && s5 == 4) { va = q0; vb = q0; }  // fx>63 single tap
                else {
                    va = WCA[s5] * q0 + WXA[s5] * q1;
                    vb = WCB[s5] * q0 + WXB[s5] * q1;
                }
                float smax, smin; int smaxl, sminl;
                if (va >= vb) { smax = va; smaxl = L0[s5]; } else { smax = vb; smaxl = L1[s5]; }
                if (va <= vb) { smin = va; sminl = L0[s5]; } else { smin = vb; sminl = L1[s5]; }
                if (smax > bmax) { bmax = smax; bmaxi = r * 64 + smaxl; }
                if (smin < bmin) { bmin = smin; bmini = oy * 1024 + cx * 64 + sminl; }
            }
        }
    }

    // --- threshold + stable descending rank sort (block = whole map) ---
    bool valid = bmax > THRESH;
    float px = valid ? (float)(cx * 64 + (bmaxi & 63)) : -1.0f;
    float py = valid ? (float)(cy * 64 + (bmaxi >> 6)) : -1.0f;
    float ps = valid ? bmax : -1.0f;
    sc[t] = ps;
    __syncthreads();
    int rank = 0;
    for (int j = 0; j < 256; ++j) {
        float sj = sc[j];
        rank += (sj > ps || (sj == ps && j < t)) ? 1 : 0;
    }
    float* o = out + m * 768 + rank * 3;
    o[0] = px; o[1] = py; o[2] = ps;

    // --- bg argmin: wave reduce + cross-wave merge; lower flat idx wins ties ---
    for (int off = 32; off > 0; off >>= 1) {
        float mv = __shfl_down(bmin, off);
        int   mj = __shfl_down(bmini, off);
        if (mv < bmin || (mv == bmin && mj < bmini)) { bmin = mv; bmini = mj; }
    }
    if ((t & 63) == 0) { wmin[t >> 6] = bmin; wmini[t >> 6] = bmini; }
    __syncthreads();
    if (t == 0) {
        float bv = wmin[0]; int bi = wmini[0];
        for (int w = 1; w < 4; ++w) {
            if (wmin[w] < bv || (wmin[w] == bv && wmini[w] < bi)) {
                bv = wmin[w]; bi = wmini[w];
            }
        }
        out[24576 + m * 2 + 0] = (float)(bi % 1024);  // x = col
        out[24576 + m * 2 + 1] = (float)(bi / 1024);  // y = row
    }
}

extern "C" void kernel_launch(void* const* d_in, const int* in_sizes, int n_in,
                              void* d_out, int out_size, void* d_ws, size_t ws_size,
                              hipStream_t stream) {
    const float* feat = (const float*)d_in[0];  // (1,256,64,64)
    const float* ref  = (const float*)d_in[1];  // (32,1,256)
    if (in_sizes[0] == 32 * 256) {  // defensive: swap if order reversed
        feat = (const float*)d_in[1];
        ref  = (const float*)d_in[0];
    }
    float* out = (float*)d_out;
    float* sim = (float*)d_ws;

    k_sim<<<dim3(32, 16), 256, 0, stream>>>(feat, ref, sim);
    k_scan_out<<<32, 256, 0, stream>>>(sim, out);
}